// Round 4
// baseline (163.173 us; speedup 1.0000x reference)
//
#include <hip/hip_runtime.h>
#include <math.h>

// Shapes: N=8, Cout=Cin=128, ks=5.
// Output [v(128), o(8), u(128), i(8), 5, 5] fp32, 26,214,400 elems.
// out[v,o,u,i,p,q] = mask[p,q] * bilinear( (1-frac)*W[g0,u,v,:,:] + frac*W[g1,u,v,:,:],
//                                          rot_o(grid_Rn)[p,q] )
//
// R3 structure: block = (o, ut, vt) owning 16u x 4v x ALL 8 i (102,400 B of
// contiguous-per-v output) so every 64 B output line has a single writer
// (R2's cross-block partial-line sharing on the 100 B i-runs caused HBM RMW).
//   per i: stage+blend 2 g-tiles -> LDS (double-buffered, 1 sync/iter)
//          fixed-k threads (coeffs in regs) tap via ds_read2, write LDS out-buf
//   final: coalesced float4 copy-out of the 25,600-float out-buf (global order).

#define TWO_PI_F 6.28318530717958647692f

__global__ __launch_bounds__(256) void rotconv_weight_kernel(
    const float* __restrict__ in_H,    // [8]
    const float* __restrict__ out_H,   // [8]
    const float* __restrict__ weight,  // [8,128,128,5,5]
    const float* __restrict__ grid_Rn, // [2,5,5]
    const float* __restrict__ mask,    // [25]
    float* __restrict__ out)
{
    __shared__ __align__(16) float s_stage[2][1600]; // blended tile, dbl-buf (12.8 KB)
    __shared__ __align__(16) float s_out[12800];     // out-buffer in global order (51.2 KB)

    const int t  = threadIdx.x;
    const int bx = blockIdx.x;
    const int vt = bx & 31;         // 32 v-tiles of 4
    const int ut = (bx >> 5) & 7;   // 8 u-tiles of 16
    const int o  = bx >> 8;
    const int u0 = ut * 16;
    const int v0 = vt * 4;

    const float ang = -out_H[o];
    float sthe, cthe;
    sincosf(ang, &sthe, &cthe);

    // ---- per-thread FIXED-k tap coefficients (depend only on o,k) ----
    const int grp = t / 25;          // 0..9 active in phase 2; 10 = idle tail
    const int k   = t - grp * 25;
    int rb0, rb1;
    float w00, w01, w10, w11;
    {
        const float X = grid_Rn[k];
        const float Y = grid_Rn[25 + k];
        const float gx = cthe * X - sthe * Y;
        const float gy = sthe * X + cthe * Y;
        const float x = (gx + 1.0f) * 2.0f;   // * 0.5 * (W-1), W=5
        const float y = (gy + 1.0f) * 2.0f;
        const float x0f = floorf(x);
        const float y0f = floorf(y);
        const float fx = x - x0f;
        const float fy = y - y0f;
        int x0 = (int)x0f; x0 = x0 < 0 ? 0 : (x0 > 4 ? 4 : x0);
        int y0 = (int)y0f; y0 = y0 < 0 ? 0 : (y0 > 4 ? 4 : y0);
        const int y1 = y0 + 1 > 4 ? 4 : y0 + 1;
        const float mk = mask[k];
        float wa = mk * (1.0f - fy) * (1.0f - fx);
        float wb = mk * (1.0f - fy) * fx;
        float wc = mk * fy * (1.0f - fx);
        float wd = mk * fy * fx;
        int xb = x0;                 // fold x-clamp: taps always (xb, xb+1)
        if (x0 == 4) { xb = 3; wb += wa; wa = 0.0f; wd += wc; wc = 0.0f; }
        rb0 = y0 * 5 + xb;
        rb1 = y1 * 5 + xb;
        w00 = wa; w01 = wb; w10 = wc; w11 = wd;
    }

    // ---- loop over i: stage+blend, then tap into the out-buffer ----
    for (int i = 0; i < 8; ++i) {
        const float theta = in_H[i] + ang;
        float m = fmodf(theta, TWO_PI_F);
        if (m < 0.0f) m += TWO_PI_F;
        const float pos  = m * (8.0f / TWO_PI_F);
        const float pf   = floorf(pos);
        const float frac = pos - pf;
        const int g0 = ((int)pf) & 7;
        const int g1 = (g0 + 1) & 7;
        const float om = 1.0f - frac;

        // stage: 16 chunks (per uu), each 4v x 25 = 100 floats contiguous,
        // source stride 3200 floats; bases 16B-aligned (v0 multiple of 4).
        float* sb = s_stage[i & 1];
        const size_t b0 = ((size_t)(g0 * 128 + u0) * 128 + v0) * 25;
        const size_t b1 = ((size_t)(g1 * 128 + u0) * 128 + v0) * 25;
        for (int f4 = t; f4 < 400; f4 += 256) {       // 400 float4 = 1600 floats
            const int chunk = f4 / 25;                // uu
            const int off4  = f4 - chunk * 25;
            const size_t a  = (size_t)chunk * 3200 + (size_t)off4 * 4;
            const float4 a0 = *reinterpret_cast<const float4*>(weight + b0 + a);
            const float4 a1 = *reinterpret_cast<const float4*>(weight + b1 + a);
            float4 bl;
            bl.x = om * a0.x + frac * a1.x;
            bl.y = om * a0.y + frac * a1.y;
            bl.z = om * a0.z + frac * a1.z;
            bl.w = om * a0.w + frac * a1.w;
            *reinterpret_cast<float4*>(sb + (size_t)f4 * 4) = bl;
        }

        __syncthreads();
        // dbl-buffer safety: staging of iter i+1 writes sb[(i+1)&1], last read
        // at iter i-1's compute, which precedes this sync in program order.

        if (grp < 10) {
            for (int run = grp; run < 64; run += 10) { // run = uu*4+vv
                const int uu = run >> 2;
                const int vv = run & 3;
                const float* tp = sb + run * 25;
                const float v00 = tp[rb0];
                const float v01 = tp[rb0 + 1];
                const float v10 = tp[rb1];
                const float v11 = tp[rb1 + 1];
                // out-buffer in global order: [vv][uu][i][k]
                s_out[((vv * 16 + uu) * 8 + i) * 25 + k] =
                    w00 * v00 + w01 * v01 + w10 * v10 + w11 * v11;
            }
        }
    }

    __syncthreads();

    // ---- copy-out: 3200 float4, fully coalesced, single-owner lines ----
    // per vv: 3200 contiguous floats at gbase(vv); 800 float4 each.
    for (int j = t; j < 3200; j += 256) {
        const int vv  = j / 800;
        const int rem = j - vv * 800;
        const float4 val = *reinterpret_cast<const float4*>(s_out + (size_t)j * 4);
        const size_t g = (((size_t)(v0 + vv) * 8 + o) * 128 + u0) * 200
                       + (size_t)rem * 4;
        *reinterpret_cast<float4*>(out + g) = val;
    }
}

extern "C" void kernel_launch(void* const* d_in, const int* in_sizes, int n_in,
                              void* d_out, int out_size, void* d_ws, size_t ws_size,
                              hipStream_t stream) {
    const float* in_H    = (const float*)d_in[0];
    const float* out_H   = (const float*)d_in[1];
    const float* weight  = (const float*)d_in[2];
    // d_in[3] = grid_H (unused)
    const float* grid_Rn = (const float*)d_in[4];
    const float* mask    = (const float*)d_in[5];
    float* out = (float*)d_out;

    // 8 o x 8 ut x 32 vt = 2048 blocks
    rotconv_weight_kernel<<<dim3(2048), dim3(256), 0, stream>>>(
        in_H, out_H, weight, grid_Rn, mask, out);
}

// Round 5
// 149.422 us; speedup vs baseline: 1.0920x; 1.0920x over previous
//
#include <hip/hip_runtime.h>
#include <math.h>

// Shapes: N=8, Cout=Cin=128, ks=5.
// Output [v(128), o(8), u(128), i(8), 5, 5] fp32, 26,214,400 elems.
// out[v,o,u,i,p,q] = mask[p,q] * bilinear( (1-f)*W[g0,u,v,:,:] + f*W[g1,u,v,:,:],
//                                          rot_o(grid_Rn)[p,q] )
//
// R4: block = (o, ut:16u, vt:2v), ALL 8 i in-block.
//   phase 1 (once): stage raw g-tiles for ALL 8 g -> LDS (25.6 KB, padded),
//                   one __syncthreads total.
//   phase 2: thread = fixed (i,k) (200 active of 256). i fixed -> g0/g1/frac
//            in regs; k fixed -> tap offsets + 8 pre-multiplied blend weights
//            in regs. 8 FMA + 4 ds_read2 per output. Stores straight from
//            registers: lane-consecutive dwords, block-owned 64B lines
//            (adjacent-u 32B phases merge in same-L2) -> no RMW, no s_out.
// R3 lesson: 64 KB LDS out-buffer halved occupancy (19%) and added 3.7M
// bank-conflict cycles; this version uses 25.9 KB -> 6 blocks/CU.

#define TWO_PI_F 6.28318530717958647692f
#define G_STRIDE 808   // 16u*2v*25 = 800 words + 8 pad (breaks g-bank aliasing)

__global__ __launch_bounds__(256) void rotconv_weight_kernel(
    const float* __restrict__ in_H,    // [8]
    const float* __restrict__ out_H,   // [8]
    const float* __restrict__ weight,  // [8,128,128,5,5]
    const float* __restrict__ grid_Rn, // [2,5,5]
    const float* __restrict__ mask,    // [25]
    float* __restrict__ out)
{
    __shared__ __align__(16) float s_w[8 * G_STRIDE];   // 25,856 B

    const int t  = threadIdx.x;
    const int bx = blockIdx.x;
    const int vt = bx & 63;          // 64 v-tiles of 2
    const int ut = (bx >> 6) & 7;    // 8 u-tiles of 16
    const int o  = bx >> 9;
    const int u0 = ut * 16;
    const int v0 = vt * 2;

    // ---- phase 1: stage all 8 raw g-tiles, float2 loads (8B-aligned) ----
    // LDS layout: [g][u(16)][vv(2)][25] + 8 pad words per g.
    for (int j = t; j < 3200; j += 256) {            // 3200 float2 = 6400 floats
        const int chunk = j / 25;                    // (g,u): 128 chunks of 50 floats
        const int off   = j - chunk * 25;
        const int g = chunk >> 4;
        const int u = chunk & 15;
        const float2 w2 = *reinterpret_cast<const float2*>(
            weight + ((size_t)((g * 128 + u0 + u) * 128) + v0) * 25 + (size_t)off * 2);
        *reinterpret_cast<float2*>(s_w + g * G_STRIDE + u * 50 + off * 2) = w2;
    }

    // ---- per-thread fixed (i,k) coefficients (registers) ----
    const int ii = t / 25;                 // 0..7 active; 8..10 idle tail
    const int k  = t - ii * 25;
    const bool active = (t < 200);
    const int i = ii > 7 ? 7 : ii;

    const float ang = -out_H[o];

    // rotation-bin blend (per i)
    const float theta = in_H[i] + ang;
    float m = fmodf(theta, TWO_PI_F);
    if (m < 0.0f) m += TWO_PI_F;
    const float pos  = m * (8.0f / TWO_PI_F);
    const float pf   = floorf(pos);
    const float frac = pos - pf;
    const int g0 = ((int)pf) & 7;
    const int g1 = (g0 + 1) & 7;
    const float om = 1.0f - frac;

    // bilinear taps (per k), x-clamp folded so taps are adjacent pairs
    float sthe, cthe;
    sincosf(ang, &sthe, &cthe);
    const float X = grid_Rn[k];
    const float Y = grid_Rn[25 + k];
    const float gx = cthe * X - sthe * Y;
    const float gy = sthe * X + cthe * Y;
    const float x = (gx + 1.0f) * 2.0f;    // * 0.5 * (W-1), W=5
    const float y = (gy + 1.0f) * 2.0f;
    const float x0f = floorf(x);
    const float y0f = floorf(y);
    const float fx = x - x0f;              // ref uses unclamped floor for fx/fy
    const float fy = y - y0f;
    int x0 = (int)x0f; x0 = x0 < 0 ? 0 : (x0 > 4 ? 4 : x0);
    int y0 = (int)y0f; y0 = y0 < 0 ? 0 : (y0 > 4 ? 4 : y0);
    const int y1 = y0 + 1 > 4 ? 4 : y0 + 1;
    const float mk = mask[k];
    float wa = mk * (1.0f - fy) * (1.0f - fx);
    float wb = mk * (1.0f - fy) * fx;
    float wc = mk * fy * (1.0f - fx);
    float wd = mk * fy * fx;
    int xb = x0;
    if (x0 == 4) { xb = 3; wb += wa; wa = 0.0f; wd += wc; wc = 0.0f; }
    const int rb0 = y0 * 5 + xb;
    const int rb1 = y1 * 5 + xb;
    // pre-multiplied blend weights: val = sum a*W[g0] + sum b*W[g1]
    const float a00 = om * wa,  a01 = om * wb,  a10 = om * wc,  a11 = om * wd;
    const float b00 = frac * wa, b01 = frac * wb, b10 = frac * wc, b11 = frac * wd;

    __syncthreads();

    if (!active) return;

    // ---- phase 2: 32 runs (uu,vv); direct coalesced register stores ----
    const float* tg0 = s_w + g0 * G_STRIDE;
    const float* tg1 = s_w + g1 * G_STRIDE;
    // out addr: (((v0+vv)*8 + o)*128 + u0+uu)*200 + i*25 + k  ; i*25+k == t
    const size_t ob0 = (((size_t)v0 * 8 + o) * 128 + u0) * 200 + t;        // vv=0
    const size_t ob1 = ((((size_t)v0 + 1) * 8 + o) * 128 + u0) * 200 + t;  // vv=1

#pragma unroll
    for (int uu = 0; uu < 16; ++uu) {
#pragma unroll
        for (int vv = 0; vv < 2; ++vv) {
            const int run = uu * 2 + vv;
            const float* p0 = tg0 + run * 25;
            const float* p1 = tg1 + run * 25;
            const float v00 = p0[rb0], v01 = p0[rb0 + 1];
            const float v10 = p0[rb1], v11 = p0[rb1 + 1];
            const float w00 = p1[rb0], w01 = p1[rb0 + 1];
            const float w10 = p1[rb1], w11 = p1[rb1 + 1];
            const float val = a00 * v00 + a01 * v01 + a10 * v10 + a11 * v11
                            + b00 * w00 + b01 * w01 + b10 * w10 + b11 * w11;
            out[(vv ? ob1 : ob0) + (size_t)uu * 200] = val;
        }
    }
}

extern "C" void kernel_launch(void* const* d_in, const int* in_sizes, int n_in,
                              void* d_out, int out_size, void* d_ws, size_t ws_size,
                              hipStream_t stream) {
    const float* in_H    = (const float*)d_in[0];
    const float* out_H   = (const float*)d_in[1];
    const float* weight  = (const float*)d_in[2];
    // d_in[3] = grid_H (unused)
    const float* grid_Rn = (const float*)d_in[4];
    const float* mask    = (const float*)d_in[5];
    float* out = (float*)d_out;

    // 8 o x 8 ut x 64 vt = 4096 blocks
    rotconv_weight_kernel<<<dim3(4096), dim3(256), 0, stream>>>(
        in_H, out_H, weight, grid_Rn, mask, out);
}

// Round 6
// 145.558 us; speedup vs baseline: 1.1210x; 1.0265x over previous
//
#include <hip/hip_runtime.h>
#include <math.h>

// Shapes: N=8, Cout=Cin=128, ks=5.
// Output [v(128), o(8), u(128), i(8), 5, 5] fp32, 26,214,400 elems.
// out[v,o,u,i,p,q] = mask[p,q] * bilinear( (1-f)*W[g0,u,v,:,:] + f*W[g1,u,v,:,:],
//                                          rot_o(grid_Rn)[p,q] )
//
// R5: block = (o, ut:16u, vt:2v), all 8 i in-block.
//   phase 1: stage PER-I BLENDED tiles (g0/g1 folded with frac during the
//            global->LDS copy) -> phase 2 needs only 2 ds_read2 per output
//            (R4's raw-g tiles needed 4 -> LDS-pipe-bound at ~52 us).
//   phase 2: thread = fixed (i,k), 200 active. Lanes with mask==0 (12/25 of k)
//            SKIP the LDS reads (exec-masked lanes issue no bank requests);
//            reads/FMAs chunked in if(has){8 runs}, stores outside at full
//            exec -> coalesced single-owner lines (R3 lesson), vals from regs.
//   LDS 26 KB -> 6 blocks/CU. Tile stride 812: even (b64 align), %32=12
//   staggers the 3 i-group bank windows; within a group same-bank => same
//   address => broadcast (free).

#define TWO_PI_F 6.28318530717958647692f
#define T_STRIDE 812   // 800 payload words + 12 pad

__global__ __launch_bounds__(256, 6) void rotconv_weight_kernel(
    const float* __restrict__ in_H,    // [8]
    const float* __restrict__ out_H,   // [8]
    const float* __restrict__ weight,  // [8,128,128,5,5]
    const float* __restrict__ grid_Rn, // [2,5,5]
    const float* __restrict__ mask,    // [25]
    float* __restrict__ out)
{
    __shared__ __align__(16) float s_w[8 * T_STRIDE];  // 25,984 B blended tiles
    __shared__ float s_fr[8];
    __shared__ int   s_g0[8], s_g1[8];

    const int t  = threadIdx.x;
    const int bx = blockIdx.x;
    const int vt = bx & 63;          // 64 v-tiles of 2
    const int ut = (bx >> 6) & 7;    // 8 u-tiles of 16
    const int o  = bx >> 9;
    const int u0 = ut * 16;
    const int v0 = vt * 2;

    const float ang = -out_H[o];

    // ---- per-i rotation-bin params (threads 0..7) ----
    if (t < 8) {
        const float theta = in_H[t] + ang;
        float m = fmodf(theta, TWO_PI_F);
        if (m < 0.0f) m += TWO_PI_F;
        const float pos = m * (8.0f / TWO_PI_F);
        const float pf  = floorf(pos);
        s_fr[t] = pos - pf;
        const int g0 = ((int)pf) & 7;
        s_g0[t] = g0;
        s_g1[t] = (g0 + 1) & 7;
    }
    __syncthreads();

    // ---- phase 1: stage + blend per-i tiles (float2 loads, 8B-aligned) ----
    // tile layout per i: [u(16)][vv(2)][25] = 800 words; 400 float2 per i.
    for (int j = t; j < 3200; j += 256) {
        const int i2 = j / 400;
        const int r  = j - i2 * 400;
        const int u  = r / 25;
        const int e  = r - u * 25;           // float2 index within 50-word run
        const int g0 = s_g0[i2], g1 = s_g1[i2];
        const float fr = s_fr[i2], om = 1.0f - fr;
        const size_t sbase = ((size_t)((u0 + u) * 128) + v0) * 25 + (size_t)e * 2;
        const float2 a = *reinterpret_cast<const float2*>(weight + (size_t)g0 * 409600 + sbase);
        const float2 b = *reinterpret_cast<const float2*>(weight + (size_t)g1 * 409600 + sbase);
        float2 bl;
        bl.x = om * a.x + fr * b.x;
        bl.y = om * a.y + fr * b.y;
        *reinterpret_cast<float2*>(s_w + i2 * T_STRIDE + u * 50 + e * 2) = bl;
    }

    // ---- per-thread fixed (i,k) tap setup (VALU only, overlaps staging) ----
    const int ii = t / 25;                 // 0..7 real; idle tail t>=200
    const int k  = t - ii * 25;
    const int i  = ii > 7 ? 7 : ii;

    float sthe, cthe;
    sincosf(ang, &sthe, &cthe);
    const float X = grid_Rn[k];
    const float Y = grid_Rn[25 + k];
    const float gx = cthe * X - sthe * Y;
    const float gy = sthe * X + cthe * Y;
    const float x = (gx + 1.0f) * 2.0f;    // * 0.5 * (W-1), W=5
    const float y = (gy + 1.0f) * 2.0f;
    const float x0f = floorf(x);
    const float y0f = floorf(y);
    const float fx = x - x0f;              // ref: frac from unclamped floor
    const float fy = y - y0f;
    int x0 = (int)x0f; x0 = x0 < 0 ? 0 : (x0 > 4 ? 4 : x0);
    int y0 = (int)y0f; y0 = y0 < 0 ? 0 : (y0 > 4 ? 4 : y0);
    const int y1 = y0 + 1 > 4 ? 4 : y0 + 1;
    const float mk = mask[k];
    float wa = mk * (1.0f - fy) * (1.0f - fx);
    float wb = mk * (1.0f - fy) * fx;
    float wc = mk * fy * (1.0f - fx);
    float wd = mk * fy * fx;
    int xb = x0;                           // fold x-clamp: taps = (xb, xb+1)
    if (x0 == 4) { xb = 3; wb += wa; wa = 0.0f; wd += wc; wc = 0.0f; }
    const int rb0 = y0 * 5 + xb;
    const int rb1 = y1 * 5 + xb;
    const bool has = (mk != 0.0f);

    __syncthreads();

    if (t >= 200) return;

    // ---- phase 2: 32 runs (uu,vv); reads mask-skipped, stores full-exec ----
    const float* sm = s_w + i * T_STRIDE;
    // out idx: (((v0+vv)*8 + o)*128 + u0+uu)*200 + i*25+k ; i*25+k == t
    const size_t ob0 = (((size_t)v0 * 8 + o) * 128 + u0) * 200 + t;  // vv=0
    const size_t ob1 = ob0 + 204800;                                 // vv=1

    for (int c = 0; c < 4; ++c) {
        float vals[8];
#pragma unroll
        for (int r8 = 0; r8 < 8; ++r8) vals[r8] = 0.0f;
        if (has) {
#pragma unroll
            for (int r8 = 0; r8 < 8; ++r8) {
                const float* tp = sm + (c * 8 + r8) * 25;  // run = c*8+r8
                vals[r8] = wa * tp[rb0] + wb * tp[rb0 + 1]
                         + wc * tp[rb1] + wd * tp[rb1 + 1];
            }
        }
#pragma unroll
        for (int r8 = 0; r8 < 8; ++r8) {
            const int run = c * 8 + r8;
            const int uu  = run >> 1;
            out[((run & 1) ? ob1 : ob0) + (size_t)uu * 200] = vals[r8];
        }
    }
}

extern "C" void kernel_launch(void* const* d_in, const int* in_sizes, int n_in,
                              void* d_out, int out_size, void* d_ws, size_t ws_size,
                              hipStream_t stream) {
    const float* in_H    = (const float*)d_in[0];
    const float* out_H   = (const float*)d_in[1];
    const float* weight  = (const float*)d_in[2];
    // d_in[3] = grid_H (unused)
    const float* grid_Rn = (const float*)d_in[4];
    const float* mask    = (const float*)d_in[5];
    float* out = (float*)d_out;

    // 8 o x 8 ut x 64 vt = 4096 blocks
    rotconv_weight_kernel<<<dim3(4096), dim3(256), 0, stream>>>(
        in_H, out_H, weight, grid_Rn, mask, out);
}